// Round 1
// baseline (871.291 us; speedup 1.0000x reference)
//
#include <hip/hip_runtime.h>
#include <hip/hip_bf16.h>
#include <math.h>

#define D 256
#define H 4
#define DH 64
#define NOUT 256

// ---------------- CSR build ----------------
__global__ void winner_kernel(const int* __restrict__ key, int* __restrict__ winner, int C){
  int i = blockIdx.x*256 + threadIdx.x;
  if (i < C){ int t = key[i]; if (t >= 0 && t < C) atomicMax(&winner[t], i); }
}

__global__ void count_kernel(const int* __restrict__ seg, int* __restrict__ counts, int M, int C){
  int i = blockIdx.x*256 + threadIdx.x;
  if (i < M){ int s = seg[i]; if (s >= 0 && s < C) atomicAdd(&counts[s], 1); }
}

__global__ __launch_bounds__(1024) void scan_kernel(const int* __restrict__ counts,
    int* __restrict__ offsets, int* __restrict__ pos, int C){
  __shared__ int wtot[16];
  __shared__ int wexcl[16];
  __shared__ int ctot;
  __shared__ int carry_s;
  int tid = threadIdx.x, lane = tid & 63, wave = tid >> 6;
  if (tid == 0) carry_s = 0;
  __syncthreads();
  for (int base = 0; base < C; base += 1024){
    int i = base + tid;
    int v = (i < C) ? counts[i] : 0;
    int x = v;
    #pragma unroll
    for (int d2 = 1; d2 < 64; d2 <<= 1){
      int t = __shfl_up(x, d2, 64);
      if (lane >= d2) x += t;
    }
    if (lane == 63) wtot[wave] = x;
    __syncthreads();
    if (wave == 0 && lane < 16){
      int t = wtot[lane]; int y = t;
      #pragma unroll
      for (int d2 = 1; d2 < 16; d2 <<= 1){
        int u = __shfl_up(y, d2, 64);
        if (lane >= d2) y += u;
      }
      wexcl[lane] = y - t;
      if (lane == 15) ctot = y;
    }
    __syncthreads();
    int carry = carry_s;
    int excl = carry + wexcl[wave] + x - v;
    if (i < C){ offsets[i] = excl; pos[i] = excl; }
    __syncthreads();
    if (tid == 0) carry_s = carry + ctot;
    __syncthreads();
  }
  if (tid == 0) offsets[C] = carry_s;
}

__global__ void fill_kernel(const int* __restrict__ seg, int* __restrict__ pos,
                            int* __restrict__ members, int M, int C){
  int i = blockIdx.x*256 + threadIdx.x;
  if (i < M){ int s = seg[i]; if (s >= 0 && s < C){ int p = atomicAdd(&pos[s], 1); members[p] = i; } }
}

// ---------------- GEMM 1: q = gather(attn_keys) @ Wq + bq   [C,256] ----------------
__global__ __launch_bounds__(256) void gemm_q(const float* __restrict__ enc,
    const int* __restrict__ rootval, const int* __restrict__ winner,
    const float* __restrict__ Wq, const float* __restrict__ bq,
    float* __restrict__ q, int C){
  __shared__ float As[16][64];
  __shared__ float Bs[16][64];
  int tid = threadIdx.x;
  int c0 = blockIdx.x*64, n0 = blockIdx.y*64;
  int lr = tid >> 2, lk4 = (tid & 3) * 4;        // A load: row, k-quad
  int br = tid >> 4, bn4 = (tid & 15) * 4;       // B load: k-row, n-quad
  int tr = tid >> 4, tc = tid & 15;              // compute tile coords
  const float* arow = nullptr;
  int gr = c0 + lr;
  if (gr < C){ int w = winner[gr]; if (w >= 0) arow = enc + (size_t)rootval[w] * D; }
  float acc[4][4] = {};
  for (int k0 = 0; k0 < D; k0 += 16){
    float4 av = make_float4(0.f, 0.f, 0.f, 0.f);
    if (arow) av = *(const float4*)(arow + k0 + lk4);
    As[lk4+0][lr] = av.x; As[lk4+1][lr] = av.y; As[lk4+2][lr] = av.z; As[lk4+3][lr] = av.w;
    float4 bv4 = *(const float4*)(Wq + (size_t)(k0 + br) * D + n0 + bn4);
    *(float4*)&Bs[br][bn4] = bv4;
    __syncthreads();
    #pragma unroll
    for (int kk = 0; kk < 16; kk++){
      float a[4], b[4];
      *(float4*)a = *(const float4*)&As[kk][tr*4];
      *(float4*)b = *(const float4*)&Bs[kk][tc*4];
      #pragma unroll
      for (int i = 0; i < 4; i++)
        #pragma unroll
        for (int j = 0; j < 4; j++) acc[i][j] += a[i] * b[j];
    }
    __syncthreads();
  }
  #pragma unroll
  for (int i = 0; i < 4; i++){
    int r = c0 + tr*4 + i;
    if (r < C){
      #pragma unroll
      for (int j = 0; j < 4; j++){
        int n = n0 + tc*4 + j;
        q[(size_t)r * D + n] = acc[i][j] + bq[n];
      }
    }
  }
}

// ---------------- GEMM 2: qk[c, h*256+e] = sum_d q[c,h*64+d] * Wk[e, h*64+d] ----------------
__global__ __launch_bounds__(256) void gemm_qk(const float* __restrict__ q,
    const float* __restrict__ Wk, float* __restrict__ qk, int C){
  __shared__ float As[16][64];
  __shared__ float Bs[16][64];
  int h = blockIdx.z;
  int tid = threadIdx.x;
  int c0 = blockIdx.x*64, e0 = blockIdx.y*64;
  int lr = tid >> 2, lk4 = (tid & 3) * 4;
  int tr = tid >> 4, tc = tid & 15;
  float acc[4][4] = {};
  for (int k0 = 0; k0 < DH; k0 += 16){
    float4 av = make_float4(0.f, 0.f, 0.f, 0.f);
    if (c0 + lr < C) av = *(const float4*)(q + (size_t)(c0 + lr) * D + h*DH + k0 + lk4);
    As[lk4+0][lr] = av.x; As[lk4+1][lr] = av.y; As[lk4+2][lr] = av.z; As[lk4+3][lr] = av.w;
    // B[d][e] = Wk[e0+e, h*64 + k0 + d] -> load rows of Wk (d contiguous), transpose into LDS
    float4 bv4 = *(const float4*)(Wk + (size_t)(e0 + lr) * D + h*DH + k0 + lk4);
    Bs[lk4+0][lr] = bv4.x; Bs[lk4+1][lr] = bv4.y; Bs[lk4+2][lr] = bv4.z; Bs[lk4+3][lr] = bv4.w;
    __syncthreads();
    #pragma unroll
    for (int kk = 0; kk < 16; kk++){
      float a[4], b[4];
      *(float4*)a = *(const float4*)&As[kk][tr*4];
      *(float4*)b = *(const float4*)&Bs[kk][tc*4];
      #pragma unroll
      for (int i = 0; i < 4; i++)
        #pragma unroll
        for (int j = 0; j < 4; j++) acc[i][j] += a[i] * b[j];
    }
    __syncthreads();
  }
  #pragma unroll
  for (int i = 0; i < 4; i++){
    int r = c0 + tr*4 + i;
    if (r < C){
      #pragma unroll
      for (int j = 0; j < 4; j++){
        int e = e0 + tc*4 + j;
        qk[(size_t)r * (H*D) + h*D + e] = acc[i][j];
      }
    }
  }
}

// ---------------- qb[c,h] = bk_h . q[c,h] ----------------
__global__ void qb_kernel(const float* __restrict__ q, const float* __restrict__ bk,
                          float* __restrict__ qb, int C){
  int i = blockIdx.x*256 + threadIdx.x;
  if (i < C*H){
    int c = i >> 2, h = i & 3;
    const float* qp = q + (size_t)c * D + h*DH;
    const float* bp = bk + h*DH;
    float s = 0.f;
    for (int d = 0; d < DH; d++) s += qp[d] * bp[d];
    qb[i] = s;
  }
}

// ---------------- Z[h*256+j][o] = sum_d Wv[j, h*64+d] * Wo[h*64+d, o] ----------------
__global__ void zcat_kernel(const float* __restrict__ Wv, const float* __restrict__ Wo,
                            float* __restrict__ Z){
  int id = blockIdx.x*256 + threadIdx.x;   // 1024*256 total
  int o = id & (NOUT-1);
  int k = id >> 8;
  int h = k >> 8, j = k & 255;
  float s = 0.f;
  for (int d = 0; d < DH; d++)
    s += Wv[(size_t)j * D + h*DH + d] * Wo[(size_t)(h*DH + d) * NOUT + o];
  Z[id] = s;
}

__global__ void bvo_kernel(const float* __restrict__ bv, const float* __restrict__ Wo,
                           float* __restrict__ bvo){
  int h = blockIdx.x, o = threadIdx.x;
  float s = 0.f;
  for (int d = 0; d < DH; d++) s += bv[h*DH + d] * Wo[(size_t)(h*DH + d) * NOUT + o];
  bvo[h*NOUT + o] = s;
}

// ---------------- fused per-segment attention pooling ----------------
// One block per segment c. Reads qk[c] (in qkS), writes Shat[c] = S/(l+eps) in-place over qkS,
// and beta[c,h] = l/(l+eps).
__global__ __launch_bounds__(256) void seg_attn(const float* __restrict__ enc,
    const int* __restrict__ astkey, const int* __restrict__ members,
    const int* __restrict__ offsets, const float* __restrict__ qb,
    float* __restrict__ qkS, float* __restrict__ beta, int C){
  const int c = blockIdx.x;
  __shared__ float qk_s[H*D];      // 4KB
  __shared__ float x_s[16][D];     // 16KB
  __shared__ float s_s[16][H];
  __shared__ float e_s[16][H];
  __shared__ float alpha_s[H];
  __shared__ float mrun[H], lrun[H];
  int tid = threadIdx.x, lane = tid & 63, wave = tid >> 6;
  ((float4*)qk_s)[tid] = ((const float4*)(qkS + (size_t)c * (H*D)))[tid];
  if (tid < H){ mrun[tid] = -INFINITY; lrun[tid] = 0.f; }
  int off = offsets[c];
  int n = offsets[c+1] - off;
  float S0 = 0.f, S1 = 0.f, S2 = 0.f, S3 = 0.f;  // S[h][tid] in registers
  __syncthreads();
  for (int base = 0; base < n; base += 16){
    int cnt = min(16, n - base);
    // Phase A: load member rows (coalesced), compute 4 head scores via wave reduce
    for (int j = wave; j < cnt; j += 4){
      int m = members[off + base + j];
      const float* xr = enc + (size_t)astkey[m] * D;
      float4 xv = *(const float4*)(xr + lane*4);
      *(float4*)&x_s[j][lane*4] = xv;
      float4 q0 = *(const float4*)&qk_s[0*D + lane*4];
      float4 q1 = *(const float4*)&qk_s[1*D + lane*4];
      float4 q2 = *(const float4*)&qk_s[2*D + lane*4];
      float4 q3 = *(const float4*)&qk_s[3*D + lane*4];
      float p0 = xv.x*q0.x + xv.y*q0.y + xv.z*q0.z + xv.w*q0.w;
      float p1 = xv.x*q1.x + xv.y*q1.y + xv.z*q1.z + xv.w*q1.w;
      float p2 = xv.x*q2.x + xv.y*q2.y + xv.z*q2.z + xv.w*q2.w;
      float p3 = xv.x*q3.x + xv.y*q3.y + xv.z*q3.z + xv.w*q3.w;
      #pragma unroll
      for (int d2 = 32; d2 >= 1; d2 >>= 1){
        p0 += __shfl_xor(p0, d2, 64);
        p1 += __shfl_xor(p1, d2, 64);
        p2 += __shfl_xor(p2, d2, 64);
        p3 += __shfl_xor(p3, d2, 64);
      }
      if (lane == 0){
        s_s[j][0] = (p0 + qb[c*H + 0]) * 0.125f;
        s_s[j][1] = (p1 + qb[c*H + 1]) * 0.125f;
        s_s[j][2] = (p2 + qb[c*H + 2]) * 0.125f;
        s_s[j][3] = (p3 + qb[c*H + 3]) * 0.125f;
      }
    }
    __syncthreads();
    // Phase B: online softmax bookkeeping, one thread per head
    if (tid < H){
      int h = tid;
      float cm = -INFINITY;
      for (int j = 0; j < cnt; j++) cm = fmaxf(cm, s_s[j][h]);
      float nm = fmaxf(mrun[h], cm);
      float alpha = __expf(mrun[h] - nm);   // exp(-inf)=0 on first chunk
      float sum = 0.f;
      for (int j = 0; j < cnt; j++){
        float e = __expf(s_s[j][h] - nm);
        e_s[j][h] = e;
        sum += e;
      }
      lrun[h] = lrun[h] * alpha + sum;
      mrun[h] = nm;
      alpha_s[h] = alpha;
    }
    __syncthreads();
    // Phase C: accumulate S (each thread owns column d=tid for all 4 heads)
    {
      float a0 = alpha_s[0], a1 = alpha_s[1], a2 = alpha_s[2], a3 = alpha_s[3];
      S0 *= a0; S1 *= a1; S2 *= a2; S3 *= a3;
      for (int j = 0; j < cnt; j++){
        float xv = x_s[j][tid];
        S0 += e_s[j][0] * xv;
        S1 += e_s[j][1] * xv;
        S2 += e_s[j][2] * xv;
        S3 += e_s[j][3] * xv;
      }
    }
    __syncthreads();
  }
  float inv0 = 1.f / (lrun[0] + 1e-9f);
  float inv1 = 1.f / (lrun[1] + 1e-9f);
  float inv2 = 1.f / (lrun[2] + 1e-9f);
  float inv3 = 1.f / (lrun[3] + 1e-9f);
  float* Sout = qkS + (size_t)c * (H*D);
  Sout[0*D + tid] = S0 * inv0;
  Sout[1*D + tid] = S1 * inv1;
  Sout[2*D + tid] = S2 * inv2;
  Sout[3*D + tid] = S3 * inv3;
  if (tid < H) beta[c*H + tid] = lrun[tid] / (lrun[tid] + 1e-9f);
}

// ---------------- GEMM 3: out = Shat[C,1024] @ Z[1024,256] + beta*bvo + bo ----------------
__global__ __launch_bounds__(256) void gemm_out(const float* __restrict__ S,
    const float* __restrict__ Z, const float* __restrict__ beta,
    const float* __restrict__ bvo, const float* __restrict__ bo,
    float* __restrict__ out, int C){
  __shared__ float As[16][64];
  __shared__ float Bs[16][64];
  int tid = threadIdx.x;
  int c0 = blockIdx.x*64, n0 = blockIdx.y*64;
  int lr = tid >> 2, lk4 = (tid & 3) * 4;
  int br = tid >> 4, bn4 = (tid & 15) * 4;
  int tr = tid >> 4, tc = tid & 15;
  float acc[4][4] = {};
  for (int k0 = 0; k0 < H*D; k0 += 16){
    float4 av = make_float4(0.f, 0.f, 0.f, 0.f);
    if (c0 + lr < C) av = *(const float4*)(S + (size_t)(c0 + lr) * (H*D) + k0 + lk4);
    As[lk4+0][lr] = av.x; As[lk4+1][lr] = av.y; As[lk4+2][lr] = av.z; As[lk4+3][lr] = av.w;
    float4 bv4 = *(const float4*)(Z + (size_t)(k0 + br) * NOUT + n0 + bn4);
    *(float4*)&Bs[br][bn4] = bv4;
    __syncthreads();
    #pragma unroll
    for (int kk = 0; kk < 16; kk++){
      float a[4], b[4];
      *(float4*)a = *(const float4*)&As[kk][tr*4];
      *(float4*)b = *(const float4*)&Bs[kk][tc*4];
      #pragma unroll
      for (int i = 0; i < 4; i++)
        #pragma unroll
        for (int j = 0; j < 4; j++) acc[i][j] += a[i] * b[j];
    }
    __syncthreads();
  }
  #pragma unroll
  for (int i = 0; i < 4; i++){
    int r = c0 + tr*4 + i;
    if (r < C){
      float b0 = beta[r*4+0], b1 = beta[r*4+1], b2 = beta[r*4+2], b3 = beta[r*4+3];
      #pragma unroll
      for (int j = 0; j < 4; j++){
        int nn = n0 + tc*4 + j;
        out[(size_t)r * NOUT + nn] = acc[i][j] + bo[nn]
            + b0*bvo[0*NOUT+nn] + b1*bvo[1*NOUT+nn] + b2*bvo[2*NOUT+nn] + b3*bvo[3*NOUT+nn];
      }
    }
  }
}

extern "C" void kernel_launch(void* const* d_in, const int* in_sizes, int n_in,
                              void* d_out, int out_size, void* d_ws, size_t ws_size,
                              hipStream_t stream) {
  const float* enc    = (const float*)d_in[0];
  const int*   astkey = (const int*)d_in[1];
  const int*   seg    = (const int*)d_in[2];
  const int*   pdgkey = (const int*)d_in[3];
  const int*   pdgval = (const int*)d_in[4];
  const float* Wq = (const float*)d_in[6];
  const float* bq = (const float*)d_in[7];
  const float* Wk = (const float*)d_in[8];
  const float* bk = (const float*)d_in[9];
  const float* Wv = (const float*)d_in[10];
  const float* bv = (const float*)d_in[11];
  const float* Wo = (const float*)d_in[12];
  const float* bo = (const float*)d_in[13];
  float* out = (float*)d_out;
  const int M = in_sizes[1];
  const int C = in_sizes[3];

  // workspace carve (256B aligned)
  char* p = (char*)d_ws;
  auto alloc = [&](size_t bytes) -> void* {
    void* r = (void*)p;
    p += (bytes + 255) / 256 * 256;
    return r;
  };
  float* q       = (float*)alloc((size_t)C * D * 4);
  float* qkS     = (float*)alloc((size_t)C * H * D * 4);   // qk, then Shat in-place
  float* qb      = (float*)alloc((size_t)C * H * 4);
  float* beta    = (float*)alloc((size_t)C * H * 4);
  float* Z       = (float*)alloc((size_t)H * D * NOUT * 4);
  float* bvo     = (float*)alloc((size_t)H * NOUT * 4);
  int*   winner  = (int*)alloc((size_t)C * 4);
  int*   counts  = (int*)alloc((size_t)C * 4);
  int*   offsets = (int*)alloc((size_t)(C + 1) * 4);
  int*   pos     = (int*)alloc((size_t)C * 4);
  int*   members = (int*)alloc((size_t)M * 4);

  hipMemsetAsync(winner, 0xFF, (size_t)C * 4, stream);   // -1
  hipMemsetAsync(counts, 0, (size_t)C * 4, stream);

  int gC = (C + 255) / 256, gM = (M + 255) / 256;
  winner_kernel<<<gC, 256, 0, stream>>>(pdgkey, winner, C);
  count_kernel<<<gM, 256, 0, stream>>>(seg, counts, M, C);
  scan_kernel<<<1, 1024, 0, stream>>>(counts, offsets, pos, C);
  fill_kernel<<<gM, 256, 0, stream>>>(seg, pos, members, M, C);

  dim3 g1((C + 63) / 64, 4);
  gemm_q<<<g1, 256, 0, stream>>>(enc, pdgval, winner, Wq, bq, q, C);
  qb_kernel<<<(C*H + 255) / 256, 256, 0, stream>>>(q, bk, qb, C);
  dim3 g2((C + 63) / 64, 4, 4);
  gemm_qk<<<g2, 256, 0, stream>>>(q, Wk, qkS, C);

  zcat_kernel<<<(H*D*NOUT) / 256, 256, 0, stream>>>(Wv, Wo, Z);
  bvo_kernel<<<H, NOUT, 0, stream>>>(bv, Wo, bvo);

  seg_attn<<<C, 256, 0, stream>>>(enc, astkey, members, offsets, qb, qkS, beta, C);

  dim3 g3((C + 63) / 64, 4);
  gemm_out<<<g3, 256, 0, stream>>>(qkS, Z, beta, bvo, bo, out, C);
}

// Round 2
// 682.941 us; speedup vs baseline: 1.2758x; 1.2758x over previous
//
#include <hip/hip_runtime.h>
#include <hip/hip_bf16.h>
#include <math.h>

#define D 256
#define H 4
#define DH 64
#define NOUT 256

// ---------------- CSR build ----------------
__global__ void winner_kernel(const int* __restrict__ key, int* __restrict__ winner, int C){
  int i = blockIdx.x*256 + threadIdx.x;
  if (i < C){ int t = key[i]; if (t >= 0 && t < C) atomicMax(&winner[t], i); }
}

__global__ void count_kernel(const int* __restrict__ seg, int* __restrict__ counts, int M, int C){
  int i = blockIdx.x*256 + threadIdx.x;
  if (i < M){ int s = seg[i]; if (s >= 0 && s < C) atomicAdd(&counts[s], 1); }
}

__global__ __launch_bounds__(1024) void scan_kernel(const int* __restrict__ counts,
    int* __restrict__ offsets, int* __restrict__ pos, int C){
  __shared__ int wtot[16];
  __shared__ int wexcl[16];
  __shared__ int ctot;
  __shared__ int carry_s;
  int tid = threadIdx.x, lane = tid & 63, wave = tid >> 6;
  if (tid == 0) carry_s = 0;
  __syncthreads();
  for (int base = 0; base < C; base += 1024){
    int i = base + tid;
    int v = (i < C) ? counts[i] : 0;
    int x = v;
    #pragma unroll
    for (int d2 = 1; d2 < 64; d2 <<= 1){
      int t = __shfl_up(x, d2, 64);
      if (lane >= d2) x += t;
    }
    if (lane == 63) wtot[wave] = x;
    __syncthreads();
    if (wave == 0 && lane < 16){
      int t = wtot[lane]; int y = t;
      #pragma unroll
      for (int d2 = 1; d2 < 16; d2 <<= 1){
        int u = __shfl_up(y, d2, 64);
        if (lane >= d2) y += u;
      }
      wexcl[lane] = y - t;
      if (lane == 15) ctot = y;
    }
    __syncthreads();
    int carry = carry_s;
    int excl = carry + wexcl[wave] + x - v;
    if (i < C){ offsets[i] = excl; pos[i] = excl; }
    __syncthreads();
    if (tid == 0) carry_s = carry + ctot;
    __syncthreads();
  }
  if (tid == 0) offsets[C] = carry_s;
}

__global__ void fill_kernel(const int* __restrict__ seg, int* __restrict__ pos,
                            int* __restrict__ members, int M, int C){
  int i = blockIdx.x*256 + threadIdx.x;
  if (i < M){ int s = seg[i]; if (s >= 0 && s < C){ int p = atomicAdd(&pos[s], 1); members[p] = i; } }
}

// ---------------- GEMM 1: q = gather(attn_keys) @ Wq + bq   [C,256] ----------------
__global__ __launch_bounds__(256) void gemm_q(const float* __restrict__ enc,
    const int* __restrict__ rootval, const int* __restrict__ winner,
    const float* __restrict__ Wq, const float* __restrict__ bq,
    float* __restrict__ q, int C){
  __shared__ float As[16][64];
  __shared__ float Bs[16][64];
  int tid = threadIdx.x;
  int c0 = blockIdx.x*64, n0 = blockIdx.y*64;
  int lr = tid >> 2, lk4 = (tid & 3) * 4;
  int br = tid >> 4, bn4 = (tid & 15) * 4;
  int tr = tid >> 4, tc = tid & 15;
  const float* arow = nullptr;
  int gr = c0 + lr;
  if (gr < C){ int w = winner[gr]; if (w >= 0) arow = enc + (size_t)rootval[w] * D; }
  float acc[4][4] = {};
  for (int k0 = 0; k0 < D; k0 += 16){
    float4 av = make_float4(0.f, 0.f, 0.f, 0.f);
    if (arow) av = *(const float4*)(arow + k0 + lk4);
    As[lk4+0][lr] = av.x; As[lk4+1][lr] = av.y; As[lk4+2][lr] = av.z; As[lk4+3][lr] = av.w;
    float4 bv4 = *(const float4*)(Wq + (size_t)(k0 + br) * D + n0 + bn4);
    *(float4*)&Bs[br][bn4] = bv4;
    __syncthreads();
    #pragma unroll
    for (int kk = 0; kk < 16; kk++){
      float a[4], b[4];
      *(float4*)a = *(const float4*)&As[kk][tr*4];
      *(float4*)b = *(const float4*)&Bs[kk][tc*4];
      #pragma unroll
      for (int i = 0; i < 4; i++)
        #pragma unroll
        for (int j = 0; j < 4; j++) acc[i][j] += a[i] * b[j];
    }
    __syncthreads();
  }
  #pragma unroll
  for (int i = 0; i < 4; i++){
    int r = c0 + tr*4 + i;
    if (r < C){
      #pragma unroll
      for (int j = 0; j < 4; j++){
        int n = n0 + tc*4 + j;
        q[(size_t)r * D + n] = acc[i][j] + bq[n];
      }
    }
  }
}

// ---------------- GEMM 2: qk[c, h*256+e] = sum_d q[c,h*64+d] * Wk[e, h*64+d] ----------------
__global__ __launch_bounds__(256) void gemm_qk(const float* __restrict__ q,
    const float* __restrict__ Wk, float* __restrict__ qk, int C){
  __shared__ float As[16][64];
  __shared__ float Bs[16][64];
  int h = blockIdx.z;
  int tid = threadIdx.x;
  int c0 = blockIdx.x*64, e0 = blockIdx.y*64;
  int lr = tid >> 2, lk4 = (tid & 3) * 4;
  int tr = tid >> 4, tc = tid & 15;
  float acc[4][4] = {};
  for (int k0 = 0; k0 < DH; k0 += 16){
    float4 av = make_float4(0.f, 0.f, 0.f, 0.f);
    if (c0 + lr < C) av = *(const float4*)(q + (size_t)(c0 + lr) * D + h*DH + k0 + lk4);
    As[lk4+0][lr] = av.x; As[lk4+1][lr] = av.y; As[lk4+2][lr] = av.z; As[lk4+3][lr] = av.w;
    float4 bv4 = *(const float4*)(Wk + (size_t)(e0 + lr) * D + h*DH + k0 + lk4);
    Bs[lk4+0][lr] = bv4.x; Bs[lk4+1][lr] = bv4.y; Bs[lk4+2][lr] = bv4.z; Bs[lk4+3][lr] = bv4.w;
    __syncthreads();
    #pragma unroll
    for (int kk = 0; kk < 16; kk++){
      float a[4], b[4];
      *(float4*)a = *(const float4*)&As[kk][tr*4];
      *(float4*)b = *(const float4*)&Bs[kk][tc*4];
      #pragma unroll
      for (int i = 0; i < 4; i++)
        #pragma unroll
        for (int j = 0; j < 4; j++) acc[i][j] += a[i] * b[j];
    }
    __syncthreads();
  }
  #pragma unroll
  for (int i = 0; i < 4; i++){
    int r = c0 + tr*4 + i;
    if (r < C){
      #pragma unroll
      for (int j = 0; j < 4; j++){
        int e = e0 + tc*4 + j;
        qk[(size_t)r * (H*D) + h*D + e] = acc[i][j];
      }
    }
  }
}

// ---------------- qb[c,h] = bk_h . q[c,h] ----------------
__global__ void qb_kernel(const float* __restrict__ q, const float* __restrict__ bk,
                          float* __restrict__ qb, int C){
  int i = blockIdx.x*256 + threadIdx.x;
  if (i < C*H){
    int c = i >> 2, h = i & 3;
    const float* qp = q + (size_t)c * D + h*DH;
    const float* bp = bk + h*DH;
    float s = 0.f;
    for (int d = 0; d < DH; d++) s += qp[d] * bp[d];
    qb[i] = s;
  }
}

// ---------------- fused per-segment attention pooling: ONE WAVE PER SEGMENT ----------------
// Wave w of each block handles segment c = blockIdx.x*4+w. qk and S accumulator in registers,
// zero barriers, online softmax replicated across lanes (wave-uniform).
// Writes Shat[c] = S/(l+eps) in-place over qkS, beta[c,h] = l/(l+eps).
__global__ __launch_bounds__(256) void seg_attn(const float* __restrict__ enc,
    const int* __restrict__ astkey, const int* __restrict__ members,
    const int* __restrict__ offsets, const float* __restrict__ qb,
    float* __restrict__ qkS, float* __restrict__ beta, int C){
  int lane = threadIdx.x & 63, wave = threadIdx.x >> 6;
  int c = blockIdx.x * 4 + wave;
  if (c >= C) return;
  float* qkc = qkS + (size_t)c * (H*D);
  // lane i holds qk[h][4i..4i+3] for each head
  float4 qk0 = ((const float4*)(qkc + 0*D))[lane];
  float4 qk1 = ((const float4*)(qkc + 1*D))[lane];
  float4 qk2 = ((const float4*)(qkc + 2*D))[lane];
  float4 qk3 = ((const float4*)(qkc + 3*D))[lane];
  float qb0 = qb[c*H+0], qb1 = qb[c*H+1], qb2 = qb[c*H+2], qb3 = qb[c*H+3];
  int off = offsets[c];
  int n = offsets[c+1] - off;
  float4 S0 = make_float4(0,0,0,0), S1 = S0, S2 = S0, S3 = S0;
  float m0 = -INFINITY, m1 = m0, m2 = m0, m3 = m0;
  float l0 = 0.f, l1 = 0.f, l2 = 0.f, l3 = 0.f;
  for (int base = 0; base < n; base += 64){
    int cnt = min(64, n - base);
    int xrow = 0;
    if (lane < cnt) xrow = astkey[members[off + base + lane]];
    int r0 = __shfl(xrow, 0, 64);
    float4 xv = ((const float4*)(enc + (size_t)r0 * D))[lane];
    for (int j = 0; j < cnt; j++){
      float4 nx = xv;
      if (j + 1 < cnt){
        int r = __shfl(xrow, j + 1, 64);
        nx = ((const float4*)(enc + (size_t)r * D))[lane];
      }
      // 4 head partial dots over this lane's 4 columns
      float p0 = xv.x*qk0.x + xv.y*qk0.y + xv.z*qk0.z + xv.w*qk0.w;
      float p1 = xv.x*qk1.x + xv.y*qk1.y + xv.z*qk1.z + xv.w*qk1.w;
      float p2 = xv.x*qk2.x + xv.y*qk2.y + xv.z*qk2.z + xv.w*qk2.w;
      float p3 = xv.x*qk3.x + xv.y*qk3.y + xv.z*qk3.z + xv.w*qk3.w;
      #pragma unroll
      for (int d2 = 1; d2 < 64; d2 <<= 1){
        p0 += __shfl_xor(p0, d2, 64);
        p1 += __shfl_xor(p1, d2, 64);
        p2 += __shfl_xor(p2, d2, 64);
        p3 += __shfl_xor(p3, d2, 64);
      }
      float s0 = (p0 + qb0) * 0.125f;
      float s1 = (p1 + qb1) * 0.125f;
      float s2 = (p2 + qb2) * 0.125f;
      float s3 = (p3 + qb3) * 0.125f;
      float nm0 = fmaxf(m0, s0), nm1 = fmaxf(m1, s1);
      float nm2 = fmaxf(m2, s2), nm3 = fmaxf(m3, s3);
      // wave-uniform rescale branch (max rarely increases)
      if ((nm0 != m0) | (nm1 != m1) | (nm2 != m2) | (nm3 != m3)){
        float a0 = __expf(m0 - nm0), a1 = __expf(m1 - nm1);
        float a2 = __expf(m2 - nm2), a3 = __expf(m3 - nm3);
        S0.x *= a0; S0.y *= a0; S0.z *= a0; S0.w *= a0;
        S1.x *= a1; S1.y *= a1; S1.z *= a1; S1.w *= a1;
        S2.x *= a2; S2.y *= a2; S2.z *= a2; S2.w *= a2;
        S3.x *= a3; S3.y *= a3; S3.z *= a3; S3.w *= a3;
        l0 *= a0; l1 *= a1; l2 *= a2; l3 *= a3;
        m0 = nm0; m1 = nm1; m2 = nm2; m3 = nm3;
      }
      float e0 = __expf(s0 - m0), e1 = __expf(s1 - m1);
      float e2 = __expf(s2 - m2), e3 = __expf(s3 - m3);
      l0 += e0; l1 += e1; l2 += e2; l3 += e3;
      S0.x += e0*xv.x; S0.y += e0*xv.y; S0.z += e0*xv.z; S0.w += e0*xv.w;
      S1.x += e1*xv.x; S1.y += e1*xv.y; S1.z += e1*xv.z; S1.w += e1*xv.w;
      S2.x += e2*xv.x; S2.y += e2*xv.y; S2.z += e2*xv.z; S2.w += e2*xv.w;
      S3.x += e3*xv.x; S3.y += e3*xv.y; S3.z += e3*xv.z; S3.w += e3*xv.w;
      xv = nx;
    }
  }
  float inv0 = 1.f / (l0 + 1e-9f), inv1 = 1.f / (l1 + 1e-9f);
  float inv2 = 1.f / (l2 + 1e-9f), inv3 = 1.f / (l3 + 1e-9f);
  S0.x *= inv0; S0.y *= inv0; S0.z *= inv0; S0.w *= inv0;
  S1.x *= inv1; S1.y *= inv1; S1.z *= inv1; S1.w *= inv1;
  S2.x *= inv2; S2.y *= inv2; S2.z *= inv2; S2.w *= inv2;
  S3.x *= inv3; S3.y *= inv3; S3.z *= inv3; S3.w *= inv3;
  ((float4*)(qkc + 0*D))[lane] = S0;
  ((float4*)(qkc + 1*D))[lane] = S1;
  ((float4*)(qkc + 2*D))[lane] = S2;
  ((float4*)(qkc + 3*D))[lane] = S3;
  if (lane == 0){
    beta[c*H+0] = l0 / (l0 + 1e-9f);
    beta[c*H+1] = l1 / (l1 + 1e-9f);
    beta[c*H+2] = l2 / (l2 + 1e-9f);
    beta[c*H+3] = l3 / (l3 + 1e-9f);
  }
}

// ---------------- GEMM 3a: pooled[c, h*64+n] = Shat[c,h,:] @ Wv[:, h*64+n] + beta[c,h]*bv[h*64+n] ----
__global__ __launch_bounds__(256) void gemm_pool(const float* __restrict__ S,
    const float* __restrict__ Wv, const float* __restrict__ beta,
    const float* __restrict__ bv, float* __restrict__ pooled, int C){
  __shared__ float As[16][64];
  __shared__ float Bs[16][64];
  int h = blockIdx.y;
  int tid = threadIdx.x;
  int c0 = blockIdx.x*64;
  int lr = tid >> 2, lk4 = (tid & 3) * 4;
  int br = tid >> 4, bn4 = (tid & 15) * 4;
  int tr = tid >> 4, tc = tid & 15;
  float acc[4][4] = {};
  for (int k0 = 0; k0 < D; k0 += 16){
    float4 av = make_float4(0.f, 0.f, 0.f, 0.f);
    if (c0 + lr < C) av = *(const float4*)(S + (size_t)(c0 + lr) * (H*D) + h*D + k0 + lk4);
    As[lk4+0][lr] = av.x; As[lk4+1][lr] = av.y; As[lk4+2][lr] = av.z; As[lk4+3][lr] = av.w;
    float4 bv4 = *(const float4*)(Wv + (size_t)(k0 + br) * D + h*DH + bn4);
    *(float4*)&Bs[br][bn4] = bv4;
    __syncthreads();
    #pragma unroll
    for (int kk = 0; kk < 16; kk++){
      float a[4], b[4];
      *(float4*)a = *(const float4*)&As[kk][tr*4];
      *(float4*)b = *(const float4*)&Bs[kk][tc*4];
      #pragma unroll
      for (int i = 0; i < 4; i++)
        #pragma unroll
        for (int j = 0; j < 4; j++) acc[i][j] += a[i] * b[j];
    }
    __syncthreads();
  }
  #pragma unroll
  for (int i = 0; i < 4; i++){
    int r = c0 + tr*4 + i;
    if (r < C){
      float bt = beta[r*H + h];
      #pragma unroll
      for (int j = 0; j < 4; j++){
        int nn = tc*4 + j;
        pooled[(size_t)r * D + h*DH + nn] = acc[i][j] + bt * bv[h*DH + nn];
      }
    }
  }
}

// ---------------- GEMM 3b: out = pooled[C,256] @ Wo[256,256] + bo ----------------
__global__ __launch_bounds__(256) void gemm_o(const float* __restrict__ P,
    const float* __restrict__ Wo, const float* __restrict__ bo,
    float* __restrict__ out, int C){
  __shared__ float As[16][64];
  __shared__ float Bs[16][64];
  int tid = threadIdx.x;
  int c0 = blockIdx.x*64, n0 = blockIdx.y*64;
  int lr = tid >> 2, lk4 = (tid & 3) * 4;
  int br = tid >> 4, bn4 = (tid & 15) * 4;
  int tr = tid >> 4, tc = tid & 15;
  float acc[4][4] = {};
  for (int k0 = 0; k0 < D; k0 += 16){
    float4 av = make_float4(0.f, 0.f, 0.f, 0.f);
    if (c0 + lr < C) av = *(const float4*)(P + (size_t)(c0 + lr) * D + k0 + lk4);
    As[lk4+0][lr] = av.x; As[lk4+1][lr] = av.y; As[lk4+2][lr] = av.z; As[lk4+3][lr] = av.w;
    float4 bv4 = *(const float4*)(Wo + (size_t)(k0 + br) * NOUT + n0 + bn4);
    *(float4*)&Bs[br][bn4] = bv4;
    __syncthreads();
    #pragma unroll
    for (int kk = 0; kk < 16; kk++){
      float a[4], b[4];
      *(float4*)a = *(const float4*)&As[kk][tr*4];
      *(float4*)b = *(const float4*)&Bs[kk][tc*4];
      #pragma unroll
      for (int i = 0; i < 4; i++)
        #pragma unroll
        for (int j = 0; j < 4; j++) acc[i][j] += a[i] * b[j];
    }
    __syncthreads();
  }
  #pragma unroll
  for (int i = 0; i < 4; i++){
    int r = c0 + tr*4 + i;
    if (r < C){
      #pragma unroll
      for (int j = 0; j < 4; j++){
        int nn = n0 + tc*4 + j;
        out[(size_t)r * NOUT + nn] = acc[i][j] + bo[nn];
      }
    }
  }
}

extern "C" void kernel_launch(void* const* d_in, const int* in_sizes, int n_in,
                              void* d_out, int out_size, void* d_ws, size_t ws_size,
                              hipStream_t stream) {
  const float* enc    = (const float*)d_in[0];
  const int*   astkey = (const int*)d_in[1];
  const int*   seg    = (const int*)d_in[2];
  const int*   pdgkey = (const int*)d_in[3];
  const int*   pdgval = (const int*)d_in[4];
  const float* Wq = (const float*)d_in[6];
  const float* bq = (const float*)d_in[7];
  const float* Wk = (const float*)d_in[8];
  const float* bk = (const float*)d_in[9];
  const float* Wv = (const float*)d_in[10];
  const float* bv = (const float*)d_in[11];
  const float* Wo = (const float*)d_in[12];
  const float* bo = (const float*)d_in[13];
  float* out = (float*)d_out;
  const int M = in_sizes[1];
  const int C = in_sizes[3];

  char* p = (char*)d_ws;
  auto alloc = [&](size_t bytes) -> void* {
    void* r = (void*)p;
    p += (bytes + 255) / 256 * 256;
    return r;
  };
  float* q       = (float*)alloc((size_t)C * D * 4);       // later reused as `pooled`
  float* qkS     = (float*)alloc((size_t)C * H * D * 4);   // qk, then Shat in-place
  float* qb      = (float*)alloc((size_t)C * H * 4);
  float* beta    = (float*)alloc((size_t)C * H * 4);
  int*   winner  = (int*)alloc((size_t)C * 4);
  int*   counts  = (int*)alloc((size_t)C * 4);
  int*   offsets = (int*)alloc((size_t)(C + 1) * 4);
  int*   pos     = (int*)alloc((size_t)C * 4);
  int*   members = (int*)alloc((size_t)M * 4);
  float* pooled  = q;  // q is dead after qb_kernel + gemm_qk

  hipMemsetAsync(winner, 0xFF, (size_t)C * 4, stream);
  hipMemsetAsync(counts, 0, (size_t)C * 4, stream);

  int gC = (C + 255) / 256, gM = (M + 255) / 256;
  winner_kernel<<<gC, 256, 0, stream>>>(pdgkey, winner, C);
  count_kernel<<<gM, 256, 0, stream>>>(seg, counts, M, C);
  scan_kernel<<<1, 1024, 0, stream>>>(counts, offsets, pos, C);
  fill_kernel<<<gM, 256, 0, stream>>>(seg, pos, members, M, C);

  dim3 g1((C + 63) / 64, 4);
  gemm_q<<<g1, 256, 0, stream>>>(enc, pdgval, winner, Wq, bq, q, C);
  qb_kernel<<<(C*H + 255) / 256, 256, 0, stream>>>(q, bk, qb, C);
  dim3 g2((C + 63) / 64, 4, 4);
  gemm_qk<<<g2, 256, 0, stream>>>(q, Wk, qkS, C);

  seg_attn<<<(C + 3) / 4, 256, 0, stream>>>(enc, astkey, members, offsets, qb, qkS, beta, C);

  dim3 gp((C + 63) / 64, 4);
  gemm_pool<<<gp, 256, 0, stream>>>(qkS, Wv, beta, bv, pooled, C);
  dim3 g3((C + 63) / 64, 4);
  gemm_o<<<g3, 256, 0, stream>>>(pooled, Wo, bo, out, C);
}

// Round 3
// 545.681 us; speedup vs baseline: 1.5967x; 1.2515x over previous
//
#include <hip/hip_runtime.h>
#include <hip/hip_bf16.h>
#include <math.h>

#define D 256
#define H 4
#define DH 64
#define NOUT 256

typedef short bf16x8 __attribute__((ext_vector_type(8)));
typedef float f32x4 __attribute__((ext_vector_type(4)));

__device__ __forceinline__ ushort f2bf(float f){
  uint b = __float_as_uint(f);
  b += 0x7FFF + ((b >> 16) & 1);   // round-to-nearest-even
  return (ushort)(b >> 16);
}
__device__ __forceinline__ float bf2f(ushort u){
  return __uint_as_float(((uint)u) << 16);
}

// ---------------- CSR build ----------------
__global__ void winner_kernel(const int* __restrict__ key, int* __restrict__ winner, int C){
  int i = blockIdx.x*256 + threadIdx.x;
  if (i < C){ int t = key[i]; if (t >= 0 && t < C) atomicMax(&winner[t], i); }
}

__global__ void count_kernel(const int* __restrict__ seg, int* __restrict__ counts, int M, int C){
  int i = blockIdx.x*256 + threadIdx.x;
  if (i < M){ int s = seg[i]; if (s >= 0 && s < C) atomicAdd(&counts[s], 1); }
}

__global__ __launch_bounds__(1024) void scan_kernel(const int* __restrict__ counts,
    int* __restrict__ offsets, int* __restrict__ pos, int C){
  __shared__ int wtot[16];
  __shared__ int wexcl[16];
  __shared__ int ctot;
  __shared__ int carry_s;
  int tid = threadIdx.x, lane = tid & 63, wave = tid >> 6;
  if (tid == 0) carry_s = 0;
  __syncthreads();
  for (int base = 0; base < C; base += 1024){
    int i = base + tid;
    int v = (i < C) ? counts[i] : 0;
    int x = v;
    #pragma unroll
    for (int d2 = 1; d2 < 64; d2 <<= 1){
      int t = __shfl_up(x, d2, 64);
      if (lane >= d2) x += t;
    }
    if (lane == 63) wtot[wave] = x;
    __syncthreads();
    if (wave == 0 && lane < 16){
      int t = wtot[lane]; int y = t;
      #pragma unroll
      for (int d2 = 1; d2 < 16; d2 <<= 1){
        int u = __shfl_up(y, d2, 64);
        if (lane >= d2) y += u;
      }
      wexcl[lane] = y - t;
      if (lane == 15) ctot = y;
    }
    __syncthreads();
    int carry = carry_s;
    int excl = carry + wexcl[wave] + x - v;
    if (i < C){ offsets[i] = excl; pos[i] = excl; }
    __syncthreads();
    if (tid == 0) carry_s = carry + ctot;
    __syncthreads();
  }
  if (tid == 0) offsets[C] = carry_s;
}

__global__ void fill_kernel(const int* __restrict__ seg, int* __restrict__ pos,
                            int* __restrict__ members, int M, int C){
  int i = blockIdx.x*256 + threadIdx.x;
  if (i < M){ int s = seg[i]; if (s >= 0 && s < C){ int p = atomicAdd(&pos[s], 1); members[p] = i; } }
}

// ---------------- weight prep: bf16 convert (+ transpose where needed) ----------------
// WqT[n][e] = Wq[e][n]; WvT[n][e] = Wv[e][n]; WoT[n][e] = Wo[e][n]; Wk16 = straight convert.
__global__ void conv_w(const float* __restrict__ Wq, const float* __restrict__ Wk,
                       const float* __restrict__ Wv, const float* __restrict__ Wo,
                       ushort* __restrict__ WqT, ushort* __restrict__ Wk16,
                       ushort* __restrict__ WvT, ushort* __restrict__ WoT){
  int id = blockIdx.x*256 + threadIdx.x;      // 65536 total
  int r = id >> 8, c = id & 255;
  WqT[id]  = f2bf(Wq[c*256 + r]);
  WvT[id]  = f2bf(Wv[c*256 + r]);
  WoT[id]  = f2bf(Wo[c*256 + r]);
  Wk16[id] = f2bf(Wk[id]);
}

// ---------------- gather attn_keys rows -> bf16 A matrix ----------------
__global__ void gather_ag(const float* __restrict__ enc, const int* __restrict__ rootval,
                          const int* __restrict__ winner, ushort* __restrict__ Ag, int C){
  int id = blockIdx.x*256 + threadIdx.x;      // C*64 total
  if (id < C*64){
    int c = id >> 6, g = id & 63;
    int w = winner[c];
    float4 v = make_float4(0.f, 0.f, 0.f, 0.f);
    if (w >= 0) v = *(const float4*)(enc + (size_t)rootval[w]*D + g*4);
    ushort4 u; u.x = f2bf(v.x); u.y = f2bf(v.y); u.z = f2bf(v.z); u.w = f2bf(v.w);
    *(ushort4*)(Ag + (size_t)c*D + g*4) = u;
  }
}

// ---------------- unified bf16 MFMA GEMM: Out[M,·] = A[M,K] @ Bt[·,K]^T (+bias|beta*bias) ----
// A row-major bf16 (row stride sA, col offset acol_h*z); Bt holds B transposed: Bt[n][k]
// (row stride sBt, rows offset btrow_h*z + blockIdx.y*64, col offset btcol_h*z).
// Out col = blockIdx.y*64 + outcol_h*z. bias indexed by global Bt row; beta by [row*H+z].
template<bool OUT_BF16>
__global__ __launch_bounds__(256) void mfma_gemm(
    const ushort* __restrict__ A, int sA, int acol_h,
    const ushort* __restrict__ Bt, int sBt, int btrow_h, int btcol_h,
    void* __restrict__ Out, int sOut, int outcol_h,
    int M, int K,
    const float* __restrict__ bias, const float* __restrict__ beta){
  __shared__ __align__(16) ushort As[64][72];
  __shared__ __align__(16) ushort Bs[64][72];
  int tid = threadIdx.x;
  int hz = blockIdx.z;
  int m0 = blockIdx.x*64;
  int acol0  = acol_h*hz;
  int btrow0 = blockIdx.y*64 + btrow_h*hz;
  int btcol0 = btcol_h*hz;
  int outcol0 = blockIdx.y*64 + outcol_h*hz;
  int w = tid >> 6, lane = tid & 63, quad = lane >> 4, l16 = lane & 15;
  int r1 = tid >> 3, c8 = (tid & 7)*8;
  f32x4 acc[4] = {};
  for (int k0 = 0; k0 < K; k0 += 64){
    const ushort* ga = A + (size_t)(m0 + r1)*sA + acol0 + k0 + c8;
    uint4 v1 = make_uint4(0,0,0,0), v2 = make_uint4(0,0,0,0);
    if (m0 + r1 < M)      v1 = *(const uint4*)ga;
    if (m0 + r1 + 32 < M) v2 = *(const uint4*)(ga + (size_t)32*sA);
    *(uint4*)&As[r1][c8]      = v1;
    *(uint4*)&As[r1+32][c8]   = v2;
    const ushort* gb = Bt + (size_t)(btrow0 + r1)*sBt + btcol0 + k0 + c8;
    *(uint4*)&Bs[r1][c8]      = *(const uint4*)gb;
    *(uint4*)&Bs[r1+32][c8]   = *(const uint4*)(gb + (size_t)32*sBt);
    __syncthreads();
    #pragma unroll
    for (int ks = 0; ks < 2; ks++){
      bf16x8 b = *(const bf16x8*)&Bs[w*16 + l16][ks*32 + quad*8];
      #pragma unroll
      for (int mt = 0; mt < 4; mt++){
        bf16x8 a = *(const bf16x8*)&As[mt*16 + l16][ks*32 + quad*8];
        acc[mt] = __builtin_amdgcn_mfma_f32_16x16x32_bf16(a, b, acc[mt], 0, 0, 0);
      }
    }
    __syncthreads();
  }
  int col = outcol0 + w*16 + l16;
  float bval = bias ? bias[btrow0 + w*16 + l16] : 0.f;
  #pragma unroll
  for (int mt = 0; mt < 4; mt++){
    #pragma unroll
    for (int r = 0; r < 4; r++){
      int row = m0 + mt*16 + quad*4 + r;
      if (row < M){
        float add = beta ? beta[row*H + hz]*bval : bval;
        float v = acc[mt][r] + add;
        if (OUT_BF16) ((ushort*)Out)[(size_t)row*sOut + col] = f2bf(v);
        else          ((float*)Out)[(size_t)row*sOut + col] = v;
      }
    }
  }
}

// ---------------- qb[c,h] = bk_h . q[c,h] (bf16 q) ----------------
__global__ void qb_kernel(const ushort* __restrict__ q16, const float* __restrict__ bk,
                          float* __restrict__ qb, int C){
  int i = blockIdx.x*256 + threadIdx.x;
  if (i < C*H){
    int c = i >> 2, h = i & 3;
    const ushort* qp = q16 + (size_t)c*D + h*DH;
    const float* bp = bk + h*DH;
    float s = 0.f;
    for (int d = 0; d < DH; d++) s += bf2f(qp[d]) * bp[d];
    qb[i] = s;
  }
}

// ---------------- fused per-segment attention pooling: ONE WAVE PER SEGMENT ----------------
__global__ __launch_bounds__(256) void seg_attn(const float* __restrict__ enc,
    const int* __restrict__ astkey, const int* __restrict__ members,
    const int* __restrict__ offsets, const float* __restrict__ qb,
    const ushort* __restrict__ qk16, ushort* __restrict__ Shat16,
    float* __restrict__ beta, int C){
  int lane = threadIdx.x & 63, wave = threadIdx.x >> 6;
  int c = blockIdx.x * 4 + wave;
  if (c >= C) return;
  const ushort4* qp = (const ushort4*)(qk16 + (size_t)c * (H*D));
  ushort4 u0 = qp[lane], u1 = qp[64 + lane], u2 = qp[128 + lane], u3 = qp[192 + lane];
  float4 qk0 = make_float4(bf2f(u0.x), bf2f(u0.y), bf2f(u0.z), bf2f(u0.w));
  float4 qk1 = make_float4(bf2f(u1.x), bf2f(u1.y), bf2f(u1.z), bf2f(u1.w));
  float4 qk2 = make_float4(bf2f(u2.x), bf2f(u2.y), bf2f(u2.z), bf2f(u2.w));
  float4 qk3 = make_float4(bf2f(u3.x), bf2f(u3.y), bf2f(u3.z), bf2f(u3.w));
  float qb0 = qb[c*H+0], qb1 = qb[c*H+1], qb2 = qb[c*H+2], qb3 = qb[c*H+3];
  int off = offsets[c];
  int n = offsets[c+1] - off;
  float4 S0 = make_float4(0,0,0,0), S1 = S0, S2 = S0, S3 = S0;
  float m0 = -INFINITY, m1 = m0, m2 = m0, m3 = m0;
  float l0 = 0.f, l1 = 0.f, l2 = 0.f, l3 = 0.f;
  for (int base = 0; base < n; base += 64){
    int cnt = min(64, n - base);
    int xrow = 0;
    if (lane < cnt) xrow = astkey[members[off + base + lane]];
    int r0 = __shfl(xrow, 0, 64);
    float4 xv = ((const float4*)(enc + (size_t)r0 * D))[lane];
    for (int j = 0; j < cnt; j++){
      float4 nx = xv;
      if (j + 1 < cnt){
        int r = __shfl(xrow, j + 1, 64);
        nx = ((const float4*)(enc + (size_t)r * D))[lane];
      }
      float p0 = xv.x*qk0.x + xv.y*qk0.y + xv.z*qk0.z + xv.w*qk0.w;
      float p1 = xv.x*qk1.x + xv.y*qk1.y + xv.z*qk1.z + xv.w*qk1.w;
      float p2 = xv.x*qk2.x + xv.y*qk2.y + xv.z*qk2.z + xv.w*qk2.w;
      float p3 = xv.x*qk3.x + xv.y*qk3.y + xv.z*qk3.z + xv.w*qk3.w;
      #pragma unroll
      for (int d2 = 1; d2 < 64; d2 <<= 1){
        p0 += __shfl_xor(p0, d2, 64);
        p1 += __shfl_xor(p1, d2, 64);
        p2 += __shfl_xor(p2, d2, 64);
        p3 += __shfl_xor(p3, d2, 64);
      }
      float s0 = (p0 + qb0) * 0.125f;
      float s1 = (p1 + qb1) * 0.125f;
      float s2 = (p2 + qb2) * 0.125f;
      float s3 = (p3 + qb3) * 0.125f;
      float nm0 = fmaxf(m0, s0), nm1 = fmaxf(m1, s1);
      float nm2 = fmaxf(m2, s2), nm3 = fmaxf(m3, s3);
      if ((nm0 != m0) | (nm1 != m1) | (nm2 != m2) | (nm3 != m3)){
        float a0 = __expf(m0 - nm0), a1 = __expf(m1 - nm1);
        float a2 = __expf(m2 - nm2), a3 = __expf(m3 - nm3);
        S0.x *= a0; S0.y *= a0; S0.z *= a0; S0.w *= a0;
        S1.x *= a1; S1.y *= a1; S1.z *= a1; S1.w *= a1;
        S2.x *= a2; S2.y *= a2; S2.z *= a2; S2.w *= a2;
        S3.x *= a3; S3.y *= a3; S3.z *= a3; S3.w *= a3;
        l0 *= a0; l1 *= a1; l2 *= a2; l3 *= a3;
        m0 = nm0; m1 = nm1; m2 = nm2; m3 = nm3;
      }
      float e0 = __expf(s0 - m0), e1 = __expf(s1 - m1);
      float e2 = __expf(s2 - m2), e3 = __expf(s3 - m3);
      l0 += e0; l1 += e1; l2 += e2; l3 += e3;
      S0.x += e0*xv.x; S0.y += e0*xv.y; S0.z += e0*xv.z; S0.w += e0*xv.w;
      S1.x += e1*xv.x; S1.y += e1*xv.y; S1.z += e1*xv.z; S1.w += e1*xv.w;
      S2.x += e2*xv.x; S2.y += e2*xv.y; S2.z += e2*xv.z; S2.w += e2*xv.w;
      S3.x += e3*xv.x; S3.y += e3*xv.y; S3.z += e3*xv.z; S3.w += e3*xv.w;
      xv = nx;
    }
  }
  float inv0 = 1.f / (l0 + 1e-9f), inv1 = 1.f / (l1 + 1e-9f);
  float inv2 = 1.f / (l2 + 1e-9f), inv3 = 1.f / (l3 + 1e-9f);
  ushort4* sp = (ushort4*)(Shat16 + (size_t)c * (H*D));
  ushort4 o0, o1, o2, o3;
  o0.x = f2bf(S0.x*inv0); o0.y = f2bf(S0.y*inv0); o0.z = f2bf(S0.z*inv0); o0.w = f2bf(S0.w*inv0);
  o1.x = f2bf(S1.x*inv1); o1.y = f2bf(S1.y*inv1); o1.z = f2bf(S1.z*inv1); o1.w = f2bf(S1.w*inv1);
  o2.x = f2bf(S2.x*inv2); o2.y = f2bf(S2.y*inv2); o2.z = f2bf(S2.z*inv2); o2.w = f2bf(S2.w*inv2);
  o3.x = f2bf(S3.x*inv3); o3.y = f2bf(S3.y*inv3); o3.z = f2bf(S3.z*inv3); o3.w = f2bf(S3.w*inv3);
  sp[lane] = o0; sp[64+lane] = o1; sp[128+lane] = o2; sp[192+lane] = o3;
  if (lane == 0){
    beta[c*H+0] = l0 / (l0 + 1e-9f);
    beta[c*H+1] = l1 / (l1 + 1e-9f);
    beta[c*H+2] = l2 / (l2 + 1e-9f);
    beta[c*H+3] = l3 / (l3 + 1e-9f);
  }
}

extern "C" void kernel_launch(void* const* d_in, const int* in_sizes, int n_in,
                              void* d_out, int out_size, void* d_ws, size_t ws_size,
                              hipStream_t stream) {
  const float* enc    = (const float*)d_in[0];
  const int*   astkey = (const int*)d_in[1];
  const int*   seg    = (const int*)d_in[2];
  const int*   pdgkey = (const int*)d_in[3];
  const int*   pdgval = (const int*)d_in[4];
  const float* Wq = (const float*)d_in[6];
  const float* bq = (const float*)d_in[7];
  const float* Wk = (const float*)d_in[8];
  const float* bk = (const float*)d_in[9];
  const float* Wv = (const float*)d_in[10];
  const float* bv = (const float*)d_in[11];
  const float* Wo = (const float*)d_in[12];
  const float* bo = (const float*)d_in[13];
  float* out = (float*)d_out;
  const int M = in_sizes[1];
  const int C = in_sizes[3];

  char* p = (char*)d_ws;
  auto alloc = [&](size_t bytes) -> void* {
    void* r = (void*)p;
    p += (bytes + 255) / 256 * 256;
    return r;
  };
  ushort* Ag      = (ushort*)alloc((size_t)C * D * 2);
  ushort* q16     = (ushort*)alloc((size_t)C * D * 2);
  ushort* qk16    = (ushort*)alloc((size_t)C * H * D * 2);
  ushort* Shat16  = (ushort*)alloc((size_t)C * H * D * 2);
  ushort* pooled16= (ushort*)alloc((size_t)C * D * 2);
  float*  qb      = (float*)alloc((size_t)C * H * 4);
  float*  beta    = (float*)alloc((size_t)C * H * 4);
  ushort* WqT     = (ushort*)alloc((size_t)D * D * 2);
  ushort* Wk16    = (ushort*)alloc((size_t)D * D * 2);
  ushort* WvT     = (ushort*)alloc((size_t)D * D * 2);
  ushort* WoT     = (ushort*)alloc((size_t)D * D * 2);
  int*   winner   = (int*)alloc((size_t)C * 4);
  int*   counts   = (int*)alloc((size_t)C * 4);
  int*   offsets  = (int*)alloc((size_t)(C + 1) * 4);
  int*   pos      = (int*)alloc((size_t)C * 4);
  int*   members  = (int*)alloc((size_t)M * 4);

  hipMemsetAsync(winner, 0xFF, (size_t)C * 4, stream);
  hipMemsetAsync(counts, 0, (size_t)C * 4, stream);

  int gC = (C + 255) / 256, gM = (M + 255) / 256;
  winner_kernel<<<gC, 256, 0, stream>>>(pdgkey, winner, C);
  count_kernel<<<gM, 256, 0, stream>>>(seg, counts, M, C);
  scan_kernel<<<1, 1024, 0, stream>>>(counts, offsets, pos, C);
  fill_kernel<<<gM, 256, 0, stream>>>(seg, pos, members, M, C);

  conv_w<<<(D*D)/256, 256, 0, stream>>>(Wq, Wk, Wv, Wo, WqT, Wk16, WvT, WoT);
  gather_ag<<<(C*64 + 255)/256, 256, 0, stream>>>(enc, pdgval, winner, Ag, C);

  int mt = (C + 63) / 64;
  // q16 = Ag @ Wq + bq                         [C,256] bf16
  mfma_gemm<true><<<dim3(mt,4,1), 256, 0, stream>>>(
      Ag, D, 0,  WqT, D, 0, 0,  q16, D, 0,  C, D, bq, nullptr);
  qb_kernel<<<(C*H + 255)/256, 256, 0, stream>>>(q16, bk, qb, C);
  // qk16[c, h*256+e] = q16[c,h*64:+64] @ Wk[e,h*64:+64]^T     [C,1024] bf16
  mfma_gemm<true><<<dim3(mt,4,4), 256, 0, stream>>>(
      q16, D, DH,  Wk16, D, 0, DH,  qk16, H*D, D,  C, DH, nullptr, nullptr);

  seg_attn<<<(C + 3)/4, 256, 0, stream>>>(enc, astkey, members, offsets, qb, qk16, Shat16, beta, C);

  // pooled16[c, h*64+n] = Shat[c,h*256:+256] @ Wv[:, h*64+n] + beta[c,h]*bv[h*64+n]
  mfma_gemm<true><<<dim3(mt,1,4), 256, 0, stream>>>(
      Shat16, H*D, D,  WvT, D, DH, 0,  pooled16, D, DH,  C, D, bv, beta);
  // out = pooled @ Wo + bo                     [C,256] fp32
  mfma_gemm<false><<<dim3(mt,4,1), 256, 0, stream>>>(
      pooled16, D, 0,  WoT, D, 0, 0,  out, NOUT, 0,  C, D, bo, nullptr);
}

// Round 4
// 518.010 us; speedup vs baseline: 1.6820x; 1.0534x over previous
//
#include <hip/hip_runtime.h>
#include <hip/hip_bf16.h>
#include <math.h>

#define D 256
#define H 4
#define DH 64
#define NOUT 256

typedef short bf16x8 __attribute__((ext_vector_type(8)));
typedef float f32x4 __attribute__((ext_vector_type(4)));

__device__ __forceinline__ ushort f2bf(float f){
  uint b = __float_as_uint(f);
  b += 0x7FFF + ((b >> 16) & 1);   // round-to-nearest-even
  return (ushort)(b >> 16);
}
__device__ __forceinline__ float bf2f(ushort u){
  return __uint_as_float(((uint)u) << 16);
}

// ---------------- CSR build ----------------
__global__ void winner_kernel(const int* __restrict__ key, int* __restrict__ winner, int C){
  int i = blockIdx.x*256 + threadIdx.x;
  if (i < C){ int t = key[i]; if (t >= 0 && t < C) atomicMax(&winner[t], i); }
}

__global__ void count_kernel(const int* __restrict__ seg, int* __restrict__ counts, int M, int C){
  int i = blockIdx.x*256 + threadIdx.x;
  if (i < M){ int s = seg[i]; if (s >= 0 && s < C) atomicAdd(&counts[s], 1); }
}

// hierarchical scan: scan1 (block-local exclusive + block totals), scan2 (scan totals), scan3 (add)
__global__ __launch_bounds__(1024) void scan1_kernel(const int* __restrict__ counts,
    int* __restrict__ loc, int* __restrict__ btot, int C){
  __shared__ int wtot[16];
  __shared__ int wexcl[16];
  int tid = threadIdx.x, lane = tid & 63, wv = tid >> 6;
  int i = blockIdx.x*1024 + tid;
  int v = (i < C) ? counts[i] : 0;
  int x = v;
  #pragma unroll
  for (int d2 = 1; d2 < 64; d2 <<= 1){
    int t = __shfl_up(x, d2, 64);
    if (lane >= d2) x += t;
  }
  if (lane == 63) wtot[wv] = x;
  __syncthreads();
  if (wv == 0 && lane < 16){
    int t = wtot[lane]; int y = t;
    #pragma unroll
    for (int d2 = 1; d2 < 16; d2 <<= 1){
      int u = __shfl_up(y, d2, 64);
      if (lane >= d2) y += u;
    }
    wexcl[lane] = y - t;
    if (lane == 15) btot[blockIdx.x] = y;
  }
  __syncthreads();
  if (i < C) loc[i] = wexcl[wv] + x - v;
}

__global__ void scan2_kernel(const int* __restrict__ btot, int* __restrict__ bexcl,
                             int nb, int* __restrict__ offsets, int C){
  int lane = threadIdx.x;             // 64 threads, nb <= 64
  int v = (lane < nb) ? btot[lane] : 0;
  int x = v;
  #pragma unroll
  for (int d2 = 1; d2 < 64; d2 <<= 1){
    int t = __shfl_up(x, d2, 64);
    if (lane >= d2) x += t;
  }
  if (lane < nb) bexcl[lane] = x - v;
  if (lane == 63) offsets[C] = x;     // grand total
}

__global__ void scan3_kernel(const int* __restrict__ loc, const int* __restrict__ bexcl,
                             int* __restrict__ offsets, int* __restrict__ pos, int C){
  int i = blockIdx.x*256 + threadIdx.x;
  if (i < C){ int o = loc[i] + bexcl[i >> 10]; offsets[i] = o; pos[i] = o; }
}

__global__ void fill_kernel(const int* __restrict__ seg, int* __restrict__ pos,
                            int* __restrict__ members, int M, int C){
  int i = blockIdx.x*256 + threadIdx.x;
  if (i < M){ int s = seg[i]; if (s >= 0 && s < C){ int p = atomicAdd(&pos[s], 1); members[p] = i; } }
}

// ---------------- weight prep ----------------
__global__ void conv3_kernel(const float* __restrict__ Wq, const float* __restrict__ Wk,
                             const float* __restrict__ Wv,
                             ushort* __restrict__ Wq16, ushort* __restrict__ Wk16,
                             ushort* __restrict__ Wv16){
  int id = blockIdx.x*256 + threadIdx.x;   // 65536
  Wq16[id] = f2bf(Wq[id]);
  Wk16[id] = f2bf(Wk[id]);
  Wv16[id] = f2bf(Wv[id]);
}

__global__ __launch_bounds__(256) void transpose_wo(const float* __restrict__ Wo,
                                                    ushort* __restrict__ WoT16){
  __shared__ float t[64][65];
  int tid = threadIdx.x;
  int r = tid >> 6, cc = tid & 63;
  int bx = blockIdx.x, by = blockIdx.y;
  #pragma unroll
  for (int rr = 0; rr < 64; rr += 4)
    t[rr + r][cc] = Wo[(size_t)(by*64 + rr + r)*256 + bx*64 + cc];
  __syncthreads();
  #pragma unroll
  for (int rr = 0; rr < 64; rr += 4)
    WoT16[(size_t)(bx*64 + rr + r)*256 + by*64 + cc] = f2bf(t[cc][rr + r]);
}

// wqbk[h*256+k] = Wq[k,64h:]·bk_h ; bvo[h*256+o] = bv_h·Wo[64h:,o] ;
// bqk[h*256+e] = bq_h·Wk[e,64h:] ; cbh[h] = bq_h·bk_h
__global__ void prep_small(const float* __restrict__ Wq, const float* __restrict__ Wk,
                           const float* __restrict__ Wo, const float* __restrict__ bq,
                           const float* __restrict__ bk, const float* __restrict__ bv,
                           float* __restrict__ wqbk, float* __restrict__ bvo,
                           float* __restrict__ bqk, float* __restrict__ cbh){
  int id = blockIdx.x*256 + threadIdx.x;
  if (id < 1024){
    int h = id >> 8, k = id & 255;
    float s = 0.f;
    for (int d = 0; d < DH; d++) s += Wq[(size_t)k*256 + h*64 + d] * bk[h*64 + d];
    wqbk[id] = s;
  } else if (id < 2048){
    int t = id - 1024; int h = t >> 8, o = t & 255;
    float s = 0.f;
    for (int d = 0; d < DH; d++) s += bv[h*64 + d] * Wo[(size_t)(h*64 + d)*256 + o];
    bvo[t] = s;
  } else if (id < 3072){
    int t = id - 2048; int h = t >> 8, e = t & 255;
    float s = 0.f;
    for (int d = 0; d < DH; d++) s += bq[h*64 + d] * Wk[(size_t)e*256 + h*64 + d];
    bqk[t] = s;
  } else if (id < 3076){
    int h = id - 3072;
    float s = 0.f;
    for (int d = 0; d < DH; d++) s += bq[h*64 + d] * bk[h*64 + d];
    cbh[h] = s;
  }
}

// ---------------- gather attn_keys rows -> bf16 A matrix ----------------
__global__ void gather_ag(const float* __restrict__ enc, const int* __restrict__ rootval,
                          const int* __restrict__ winner, ushort* __restrict__ Ag, int C){
  int id = blockIdx.x*256 + threadIdx.x;      // C*64 total
  if (id < C*64){
    int c = id >> 6, g = id & 63;
    int w = winner[c];
    float4 v = make_float4(0.f, 0.f, 0.f, 0.f);
    if (w >= 0) v = *(const float4*)(enc + (size_t)rootval[w]*D + g*4);
    ushort4 u; u.x = f2bf(v.x); u.y = f2bf(v.y); u.z = f2bf(v.z); u.w = f2bf(v.w);
    *(ushort4*)(Ag + (size_t)c*D + g*4) = u;
  }
}

// ---------------- unified bf16 MFMA GEMM ----------------
// Out[outrow_h*z + row, outcol_h*z + y*64 + n] = sum_k A[row, acol_h*z + k] * Bt[btrow_h*z + y*64 + n, btcol_h*z + k]
// bias indexed by (btrow_h*z + y*64 + n); bvo4/beta4: += sum_h beta4[row*4+h]*bvo4[h*256 + y*64+n]
template<bool OUT_BF16>
__global__ __launch_bounds__(256) void mfma_gemm(
    const ushort* __restrict__ A, int sA, int acol_h,
    const ushort* __restrict__ Bt, int sBt, int btrow_h, int btcol_h,
    void* __restrict__ Out, int sOut, int outrow_h, int outcol_h,
    int M, int K,
    const float* __restrict__ bias, const float* __restrict__ beta4,
    const float* __restrict__ bvo4){
  __shared__ __align__(16) ushort As[64][72];
  __shared__ __align__(16) ushort Bs[64][72];
  int tid = threadIdx.x;
  int hz = blockIdx.z;
  int m0 = blockIdx.x*64;
  int acol0  = acol_h*hz;
  int btrow0 = blockIdx.y*64 + btrow_h*hz;
  int btcol0 = btcol_h*hz;
  int outrow0 = outrow_h*hz;
  int outcol0 = blockIdx.y*64 + outcol_h*hz;
  int w = tid >> 6, lane = tid & 63, quad = lane >> 4, l16 = lane & 15;
  int r1 = tid >> 3, c8 = (tid & 7)*8;
  f32x4 acc[4] = {};
  for (int k0 = 0; k0 < K; k0 += 64){
    const ushort* ga = A + (size_t)(m0 + r1)*sA + acol0 + k0 + c8;
    uint4 v1 = make_uint4(0,0,0,0), v2 = make_uint4(0,0,0,0);
    if (m0 + r1 < M)      v1 = *(const uint4*)ga;
    if (m0 + r1 + 32 < M) v2 = *(const uint4*)(ga + (size_t)32*sA);
    *(uint4*)&As[r1][c8]      = v1;
    *(uint4*)&As[r1+32][c8]   = v2;
    const ushort* gb = Bt + (size_t)(btrow0 + r1)*sBt + btcol0 + k0 + c8;
    *(uint4*)&Bs[r1][c8]      = *(const uint4*)gb;
    *(uint4*)&Bs[r1+32][c8]   = *(const uint4*)(gb + (size_t)32*sBt);
    __syncthreads();
    #pragma unroll
    for (int ks = 0; ks < 2; ks++){
      bf16x8 b = *(const bf16x8*)&Bs[w*16 + l16][ks*32 + quad*8];
      #pragma unroll
      for (int mt = 0; mt < 4; mt++){
        bf16x8 a = *(const bf16x8*)&As[mt*16 + l16][ks*32 + quad*8];
        acc[mt] = __builtin_amdgcn_mfma_f32_16x16x32_bf16(a, b, acc[mt], 0, 0, 0);
      }
    }
    __syncthreads();
  }
  int col = outcol0 + w*16 + l16;
  int bcol = btrow0 + w*16 + l16;
  float bval = bias ? bias[bcol] : 0.f;
  #pragma unroll
  for (int mt = 0; mt < 4; mt++){
    #pragma unroll
    for (int r = 0; r < 4; r++){
      int row = m0 + mt*16 + quad*4 + r;
      if (row < M){
        float v = acc[mt][r] + bval;
        if (bvo4){
          v += beta4[row*4+0]*bvo4[0*256 + bcol] + beta4[row*4+1]*bvo4[1*256 + bcol]
             + beta4[row*4+2]*bvo4[2*256 + bcol] + beta4[row*4+3]*bvo4[3*256 + bcol];
        }
        if (OUT_BF16) ((ushort*)Out)[(size_t)(outrow0 + row)*sOut + col] = f2bf(v);
        else          ((float*)Out)[(size_t)(outrow0 + row)*sOut + col] = v;
      }
    }
  }
}

// ---------------- fused per-segment attention pooling: wave/segment, half-wave pairs ----------
// 2 members per iteration (32 lanes x 8 cols each); plain exp (scores |s|<~0.6, max-free is
// exact vs reference within fp rounding); qb computed inline from Ag·wqbk + cbh.
__global__ __launch_bounds__(256) void seg_attn(const float* __restrict__ enc,
    const int* __restrict__ astkey, const int* __restrict__ members,
    const int* __restrict__ offsets, const ushort* __restrict__ Ag,
    const float* __restrict__ wqbk, const float* __restrict__ cbh,
    const ushort* __restrict__ qk16, ushort* __restrict__ Shat16,
    float* __restrict__ beta, int C){
  int lane = threadIdx.x & 63, wave = threadIdx.x >> 6;
  int c = blockIdx.x*4 + wave;
  if (c >= C) return;
  int half = lane >> 5, sl = lane & 31;
  // qk fragment: lane holds cols [sl*8, sl*8+8) for all 4 heads (duplicated across halves)
  float qk[4][8];
  const ushort* qkp = qk16 + (size_t)c*1024 + sl*8;
  #pragma unroll
  for (int h = 0; h < 4; h++){
    uint4 u = *(const uint4*)(qkp + h*256);
    qk[h][0]=__uint_as_float(u.x<<16); qk[h][1]=__uint_as_float(u.x&0xffff0000u);
    qk[h][2]=__uint_as_float(u.y<<16); qk[h][3]=__uint_as_float(u.y&0xffff0000u);
    qk[h][4]=__uint_as_float(u.z<<16); qk[h][5]=__uint_as_float(u.z&0xffff0000u);
    qk[h][6]=__uint_as_float(u.w<<16); qk[h][7]=__uint_as_float(u.w&0xffff0000u);
  }
  // qb inline: qb_h = Ag[c]·wqbk_h + cbh_h
  float qbv[4];
  {
    uint4 a = *(const uint4*)(Ag + (size_t)c*256 + sl*8);
    float av[8];
    av[0]=__uint_as_float(a.x<<16); av[1]=__uint_as_float(a.x&0xffff0000u);
    av[2]=__uint_as_float(a.y<<16); av[3]=__uint_as_float(a.y&0xffff0000u);
    av[4]=__uint_as_float(a.z<<16); av[5]=__uint_as_float(a.z&0xffff0000u);
    av[6]=__uint_as_float(a.w<<16); av[7]=__uint_as_float(a.w&0xffff0000u);
    #pragma unroll
    for (int h = 0; h < 4; h++){
      const float* wp = wqbk + h*256 + sl*8;
      float p = av[0]*wp[0] + av[1]*wp[1] + av[2]*wp[2] + av[3]*wp[3]
              + av[4]*wp[4] + av[5]*wp[5] + av[6]*wp[6] + av[7]*wp[7];
      #pragma unroll
      for (int d2 = 1; d2 < 32; d2 <<= 1) p += __shfl_xor(p, d2, 64);
      qbv[h] = p + cbh[h];
    }
  }
  int off = offsets[c];
  int n = offsets[c+1] - off;
  float S[4][8] = {};
  float l[4] = {0.f, 0.f, 0.f, 0.f};
  for (int base = 0; base < n; base += 64){
    int cnt = min(64, n - base);
    int xrow = 0;
    if (lane < cnt) xrow = astkey[members[off + base + lane]];
    int rA = __shfl(xrow, 0, 64);
    int rB = __shfl(xrow, (cnt > 1) ? 1 : 0, 64);
    int r = half ? rB : rA;
    const float* xp = enc + (size_t)r*256 + sl*8;
    float4 x0 = *(const float4*)xp;
    float4 x1 = *(const float4*)(xp + 4);
    for (int j = 0; j < cnt; j += 2){
      float4 nx0 = x0, nx1 = x1;
      if (j + 2 < cnt){
        int nA = __shfl(xrow, j + 2, 64);
        int nB = __shfl(xrow, (j + 3 < cnt) ? (j + 3) : (j + 2), 64);
        int nr = half ? nB : nA;
        const float* np = enc + (size_t)nr*256 + sl*8;
        nx0 = *(const float4*)np;
        nx1 = *(const float4*)(np + 4);
      }
      float x[8] = {x0.x, x0.y, x0.z, x0.w, x1.x, x1.y, x1.z, x1.w};
      float p[4];
      #pragma unroll
      for (int h = 0; h < 4; h++){
        float s = x[0]*qk[h][0] + x[1]*qk[h][1] + x[2]*qk[h][2] + x[3]*qk[h][3]
                + x[4]*qk[h][4] + x[5]*qk[h][5] + x[6]*qk[h][6] + x[7]*qk[h][7];
        p[h] = s;
      }
      #pragma unroll
      for (int d2 = 1; d2 < 32; d2 <<= 1){
        #pragma unroll
        for (int h = 0; h < 4; h++) p[h] += __shfl_xor(p[h], d2, 64);
      }
      float e[4];
      #pragma unroll
      for (int h = 0; h < 4; h++) e[h] = __expf((p[h] + qbv[h]) * 0.125f);
      if (half & (int)(j + 1 >= cnt)){ e[0] = e[1] = e[2] = e[3] = 0.f; }
      #pragma unroll
      for (int h = 0; h < 4; h++){
        l[h] += e[h];
        #pragma unroll
        for (int k = 0; k < 8; k++) S[h][k] += e[h]*x[k];
      }
      x0 = nx0; x1 = nx1;
    }
  }
  // combine the two halves
  #pragma unroll
  for (int h = 0; h < 4; h++) l[h] += __shfl_xor(l[h], 32, 64);
  #pragma unroll
  for (int h = 0; h < 4; h++){
    #pragma unroll
    for (int k = 0; k < 8; k++) S[h][k] += __shfl_xor(S[h][k], 32, 64);
  }
  float inv[4];
  #pragma unroll
  for (int h = 0; h < 4; h++) inv[h] = 1.f / (l[h] + 1e-9f);
  if (half == 0){
    ushort* sp = Shat16 + (size_t)c*1024 + sl*8;
    #pragma unroll
    for (int h = 0; h < 4; h++){
      float ih = inv[h];
      uint4 o;
      o.x = (uint)f2bf(S[h][0]*ih) | ((uint)f2bf(S[h][1]*ih) << 16);
      o.y = (uint)f2bf(S[h][2]*ih) | ((uint)f2bf(S[h][3]*ih) << 16);
      o.z = (uint)f2bf(S[h][4]*ih) | ((uint)f2bf(S[h][5]*ih) << 16);
      o.w = (uint)f2bf(S[h][6]*ih) | ((uint)f2bf(S[h][7]*ih) << 16);
      *(uint4*)(sp + h*256) = o;
    }
  }
  if (lane == 0){
    beta[c*4+0] = l[0] / (l[0] + 1e-9f);
    beta[c*4+1] = l[1] / (l[1] + 1e-9f);
    beta[c*4+2] = l[2] / (l[2] + 1e-9f);
    beta[c*4+3] = l[3] / (l[3] + 1e-9f);
  }
}

extern "C" void kernel_launch(void* const* d_in, const int* in_sizes, int n_in,
                              void* d_out, int out_size, void* d_ws, size_t ws_size,
                              hipStream_t stream) {
  const float* enc    = (const float*)d_in[0];
  const int*   astkey = (const int*)d_in[1];
  const int*   seg    = (const int*)d_in[2];
  const int*   pdgkey = (const int*)d_in[3];
  const int*   pdgval = (const int*)d_in[4];
  const float* Wq = (const float*)d_in[6];
  const float* bq = (const float*)d_in[7];
  const float* Wk = (const float*)d_in[8];
  const float* bk = (const float*)d_in[9];
  const float* Wv = (const float*)d_in[10];
  const float* bv = (const float*)d_in[11];
  const float* Wo = (const float*)d_in[12];
  const float* bo = (const float*)d_in[13];
  float* out = (float*)d_out;
  const int M = in_sizes[1];
  const int C = in_sizes[3];

  char* p = (char*)d_ws;
  auto alloc = [&](size_t bytes) -> void* {
    void* r = (void*)p;
    p += (bytes + 255) / 256 * 256;
    return r;
  };
  ushort* Ag      = (ushort*)alloc((size_t)C * D * 2);
  ushort* qk16    = (ushort*)alloc((size_t)C * H * D * 2);
  ushort* Shat16  = (ushort*)alloc((size_t)C * H * D * 2);
  float*  beta    = (float*)alloc((size_t)C * H * 4);
  ushort* Wq16    = (ushort*)alloc((size_t)D * D * 2);
  ushort* Wk16    = (ushort*)alloc((size_t)D * D * 2);
  ushort* Wv16    = (ushort*)alloc((size_t)D * D * 2);
  ushort* WoT16   = (ushort*)alloc((size_t)D * D * 2);
  ushort* Gt16    = (ushort*)alloc((size_t)H * D * D * 2);
  ushort* Zt16    = (ushort*)alloc((size_t)D * H * D * 2);
  float*  wqbk    = (float*)alloc((size_t)H * D * 4);
  float*  bvo     = (float*)alloc((size_t)H * NOUT * 4);
  float*  bqk     = (float*)alloc((size_t)H * D * 4);
  float*  cbh     = (float*)alloc((size_t)H * 4);
  int*   winner   = (int*)alloc((size_t)C * 4);
  int*   counts   = (int*)alloc((size_t)C * 4);
  int*   loc      = (int*)alloc((size_t)C * 4);
  int*   btot     = (int*)alloc((size_t)64 * 4);
  int*   bexcl    = (int*)alloc((size_t)64 * 4);
  int*   offsets  = (int*)alloc((size_t)(C + 1) * 4);
  int*   pos      = (int*)alloc((size_t)C * 4);
  int*   members  = (int*)alloc((size_t)M * 4);

  hipMemsetAsync(winner, 0xFF, (size_t)C * 4, stream);
  hipMemsetAsync(counts, 0, (size_t)C * 4, stream);

  int gC = (C + 255) / 256, gM = (M + 255) / 256;
  int nb1024 = (C + 1023) / 1024;
  winner_kernel<<<gC, 256, 0, stream>>>(pdgkey, winner, C);
  count_kernel<<<gM, 256, 0, stream>>>(seg, counts, M, C);
  scan1_kernel<<<nb1024, 1024, 0, stream>>>(counts, loc, btot, C);
  scan2_kernel<<<1, 64, 0, stream>>>(btot, bexcl, nb1024, offsets, C);
  scan3_kernel<<<gC, 256, 0, stream>>>(loc, bexcl, offsets, pos, C);
  fill_kernel<<<gM, 256, 0, stream>>>(seg, pos, members, M, C);

  conv3_kernel<<<(D*D)/256, 256, 0, stream>>>(Wq, Wk, Wv, Wq16, Wk16, Wv16);
  transpose_wo<<<dim3(4,4), 256, 0, stream>>>(Wo, WoT16);
  prep_small<<<13, 256, 0, stream>>>(Wq, Wk, Wo, bq, bk, bv, wqbk, bvo, bqk, cbh);

  // Gt[(h,e)][k] = sum_d Wq[k,64h+d]*Wk[e,64h+d]
  mfma_gemm<true><<<dim3(4,4,4), 256, 0, stream>>>(
      Wk16, D, DH,  Wq16, D, 0, DH,  Gt16, D, D, 0,  D, DH, nullptr, nullptr, nullptr);
  // Zt[o][(h,j)] = sum_d Wv[j,64h+d]*Wo[64h+d,o]
  mfma_gemm<true><<<dim3(4,4,4), 256, 0, stream>>>(
      WoT16, D, DH,  Wv16, D, 0, DH,  Zt16, H*D, 0, D,  D, DH, nullptr, nullptr, nullptr);

  gather_ag<<<(C*64 + 255)/256, 256, 0, stream>>>(enc, pdgval, winner, Ag, C);

  int mt = (C + 63) / 64;
  // qk16[c,(h,e)] = Ag[c,:] @ Gt[(h,e),:] + bqk[(h,e)]
  mfma_gemm<true><<<dim3(mt,4,4), 256, 0, stream>>>(
      Ag, D, 0,  Gt16, D, D, 0,  qk16, H*D, 0, D,  C, D, bqk, nullptr, nullptr);

  seg_attn<<<(C + 3)/4, 256, 0, stream>>>(enc, astkey, members, offsets, Ag,
                                          wqbk, cbh, qk16, Shat16, beta, C);

  // out[c,o] = Shat[c,:] @ Zt[o,:] + bo[o] + sum_h beta[c,h]*bvo[h,o]
  mfma_gemm<false><<<dim3(mt,4,1), 256, 0, stream>>>(
      Shat16, H*D, 0,  Zt16, H*D, 0, 0,  out, NOUT, 0, 0,  C, H*D, bo, beta, bvo);
}